// Round 2
// baseline (524.391 us; speedup 1.0000x reference)
//
#include <hip/hip_runtime.h>

typedef _Float16 half8 __attribute__((ext_vector_type(8)));
typedef float floatx4 __attribute__((ext_vector_type(4)));

#define DEVI __device__ __forceinline__

namespace {
constexpr int C_   = 256;
constexpr int DHW_ = 8192;
constexpr int N_   = 16384;   // rows = B*D*H*W
constexpr int NE_  = 8192;    // codebook entries
constexpr int K_   = 256;     // embedding dim

constexpr size_t LOSS_OFF  = 4194304;
constexpr size_t PERP_OFF  = 4194305;
constexpr size_t ENC_OFF   = 4194306;
constexpr size_t ENC_N     = 134217728ull;
constexpr size_t IDX_OFF   = ENC_OFF + ENC_N;

// scratch inside enc-region tail (overwritten by vq_write_enc AFTER last use)
constexpr size_t SCR_ZH   = 480ull << 20;  // 16384x256 f16 = 8 MiB
constexpr size_t SCR_ZL   = 488ull << 20;  // 8 MiB
constexpr size_t SCR_EH   = 496ull << 20;  // 8192x256 f16 = 4 MiB
constexpr size_t SCR_EL   = 500ull << 20;  // 4 MiB
constexpr size_t SCR_ZZ   = 504ull << 20;  // 16384 f32
constexpr size_t SCR_KEY  = 505ull << 20;  // 16384 u64
constexpr size_t SCR_PART = 506ull << 20;  // loss partials f32

constexpr int NLOSS_BLOCKS = 2048;
}

// ---------------- split z -> ZH/ZL (f16) + zz (f32) ----------------
// z layout [B=2][C=256][DHW=8192]; zf[n][c] = z[b][c][dhw], n = b*DHW+dhw
__global__ void vq_split_z(const float* __restrict__ z,
                           _Float16* __restrict__ ZH, _Float16* __restrict__ ZL,
                           float* __restrict__ zz) {
    __shared__ float tile[64][260];
    int n0 = blockIdx.x * 64;
    int b  = n0 >> 13;           // n0 / DHW_
    int d0 = n0 & 8191;
    const float* zb = z + (size_t)b * C_ * DHW_ + d0;
    int t  = threadIdx.x;
    int nl = t & 63, cg = t >> 6;
    for (int cc = 0; cc < 256; cc += 4) {
        int c = cc + cg;
        tile[nl][c] = zb[(size_t)c * DHW_ + nl];   // coalesced over nl
    }
    __syncthreads();
    // write split arrays coalesced (t == c)
    for (int r = 0; r < 64; ++r) {
        float v = tile[r][t];
        _Float16 h = (_Float16)v;
        _Float16 l = (_Float16)((v - (float)h) * 2048.0f);  // residual scaled 2^11
        size_t o = (size_t)(n0 + r) * K_ + t;
        ZH[o] = h;
        ZL[o] = l;
    }
    // zz: numpy-pairwise-like order; only the binade matters for argmin equivalence.
    if (t < 64) {
        float tot[2];
        for (int h = 0; h < 2; ++h) {
            float r8[8];
            #pragma unroll
            for (int k = 0; k < 8; ++k) { float x = tile[t][h*128 + k]; r8[k] = x * x; }
            for (int i = 8; i < 128; i += 8) {
                #pragma unroll
                for (int k = 0; k < 8; ++k) { float x = tile[t][h*128 + i + k]; r8[k] += x * x; }
            }
            tot[h] = ((r8[0]+r8[1]) + (r8[2]+r8[3])) + ((r8[4]+r8[5]) + (r8[6]+r8[7]));
        }
        zz[n0 + t] = tot[0] + tot[1];
    }
}

// ---------------- split codebook -> EH/EL (f16, scaled) + keys init ----------------
__global__ void vq_split_e(const float* __restrict__ cb,
                           _Float16* __restrict__ EH, _Float16* __restrict__ EL,
                           unsigned long long* __restrict__ keys) {
    int j0 = blockIdx.x * 64;
    int t  = threadIdx.x;   // t == c
    for (int i = 0; i < 64; ++i) {
        size_t o = (size_t)(j0 + i) * K_ + t;
        float v = cb[o] * 65536.0f;             // exact (pow2)
        _Float16 h = (_Float16)v;
        _Float16 l = (_Float16)((v - (float)h) * 2048.0f);  // exact residual, scaled
        EH[o] = h;
        EL[o] = l;
    }
    if (blockIdx.x < 64) keys[blockIdx.x * 256 + t] = ~0ull;
}

// ---------------- GEMM + fused argmin ----------------
// dot = acc_a*2^-16 + acc_b*2^-27 ; d = fl(zz - 2*dot) ; argmin (tie -> min j)
#define TM 128
#define TN 128
#define KC 32
#define NC 8

DEVI void stage_tile32(const char* gbase, _Float16* sbuf, int t, int kcByte) {
    // tile: 128 rows x 32 halfs (64 B/row); XOR-swizzle on the GLOBAL side,
    // linear LDS dest (global_load_lds requirement), inverse XOR on ds_read.
    #pragma unroll
    for (int i = 0; i < 2; ++i) {
        int f = i * 256 + t;        // 0..511
        int row = f >> 2;           // 0..127
        int slot = f & 3;           // 16B slot within 64B row
        int kb = (slot ^ ((row >> 1) & 3)) * 16;
        const char* gp = gbase + (size_t)row * (K_ * 2) + kcByte + kb;
        char* lp = (char*)sbuf + (size_t)f * 16;
        __builtin_amdgcn_global_load_lds((const __attribute__((address_space(1))) void*)gp,
                                         (__attribute__((address_space(3))) void*)lp,
                                         16, 0, 0);
    }
}

__launch_bounds__(256, 2)
__global__ void vq_gemm_argmin(const _Float16* __restrict__ ZH, const _Float16* __restrict__ ZL,
                               const _Float16* __restrict__ EH, const _Float16* __restrict__ EL,
                               const float* __restrict__ zz,
                               unsigned long long* __restrict__ keys) {
    __shared__ _Float16 sZH[2][TM * KC], sZL[2][TM * KC];
    __shared__ _Float16 sEH[2][TN * KC], sEL[2][TN * KC];
    __shared__ unsigned long long rowmin[TM];

    // XCD-aware bijective swizzle: 8192 blocks = 8 XCDs x 1024
    int orig = blockIdx.x;
    int wg = (orig & 7) * 1024 + (orig >> 3);
    int bm = wg & 127, bn = wg >> 7;
    int m0 = bm * TM, n0v = bn * TN;
    int t = threadIdx.x;
    int lane = t & 63, wid = t >> 6;
    int wm = wid >> 1, wn = wid & 1;      // 2x2 waves of 64x64

    const char* gZH = (const char*)(ZH + (size_t)m0 * K_);
    const char* gZL = (const char*)(ZL + (size_t)m0 * K_);
    const char* gEH = (const char*)(EH + (size_t)n0v * K_);
    const char* gEL = (const char*)(EL + (size_t)n0v * K_);

    floatx4 acc_a[4][4], acc_b[4][4];
    #pragma unroll
    for (int i = 0; i < 4; ++i)
        #pragma unroll
        for (int j = 0; j < 4; ++j) {
            acc_a[i][j] = (floatx4){0.f, 0.f, 0.f, 0.f};
            acc_b[i][j] = (floatx4){0.f, 0.f, 0.f, 0.f};
        }

    int g = lane >> 4, rr = lane & 15;
    // physical-slot byte offset within a 64B LDS row (swizzle uses only rr bits 1-2)
    int pA = (g ^ ((rr >> 1) & 3)) * 16;

    // prologue: stage chunk 0 into buf 0
    stage_tile32(gZH, sZH[0], t, 0);
    stage_tile32(gZL, sZL[0], t, 0);
    stage_tile32(gEH, sEH[0], t, 0);
    stage_tile32(gEL, sEL[0], t, 0);
    __syncthreads();   // drains vmcnt before barrier

    for (int kc = 0; kc < NC; ++kc) {
        int cur = kc & 1;
        if (kc + 1 < NC) {   // issue next-chunk staging BEFORE compute (2-phase overlap)
            int kb = (kc + 1) * (KC * 2);
            stage_tile32(gZH, sZH[cur ^ 1], t, kb);
            stage_tile32(gZL, sZL[cur ^ 1], t, kb);
            stage_tile32(gEH, sEH[cur ^ 1], t, kb);
            stage_tile32(gEL, sEL[cur ^ 1], t, kb);
        }
        half8 azh[4], azl[4], beh[4], bel[4];
        #pragma unroll
        for (int f = 0; f < 4; ++f) {
            int row = wm * 64 + f * 16 + rr;
            azh[f] = *(const half8*)((const char*)sZH[cur] + row * 64 + pA);
            azl[f] = *(const half8*)((const char*)sZL[cur] + row * 64 + pA);
            int col = wn * 64 + f * 16 + rr;
            beh[f] = *(const half8*)((const char*)sEH[cur] + col * 64 + pA);
            bel[f] = *(const half8*)((const char*)sEL[cur] + col * 64 + pA);
        }
        #pragma unroll
        for (int fi = 0; fi < 4; ++fi)
            #pragma unroll
            for (int fj = 0; fj < 4; ++fj) {
                acc_a[fi][fj] = __builtin_amdgcn_mfma_f32_16x16x32_f16(azh[fi], beh[fj], acc_a[fi][fj], 0, 0, 0);
                acc_b[fi][fj] = __builtin_amdgcn_mfma_f32_16x16x32_f16(azl[fi], beh[fj], acc_b[fi][fj], 0, 0, 0);
                acc_b[fi][fj] = __builtin_amdgcn_mfma_f32_16x16x32_f16(azh[fi], bel[fj], acc_b[fi][fj], 0, 0, 0);
            }
        __syncthreads();   // vmcnt(0)+lgkmcnt(0)+barrier: next buf ready, this buf free
    }

    if (t < TM) rowmin[t] = ~0ull;
    __syncthreads();

    constexpr float S_A = 1.0f / 65536.0f;       // 2^-16
    constexpr float S_B = 1.0f / 134217728.0f;   // 2^-27
    #pragma unroll
    for (int fi = 0; fi < 4; ++fi) {
        #pragma unroll
        for (int r = 0; r < 4; ++r) {
            int rowl = wm * 64 + fi * 16 + g * 4 + r;
            float zzv = zz[m0 + rowl];
            unsigned long long best = ~0ull;
            #pragma unroll
            for (int fj = 0; fj < 4; ++fj) {
                float dot = acc_a[fi][fj][r] * S_A + acc_b[fi][fj][r] * S_B;
                float d = zzv - 2.0f * dot;              // replicates ref fl(zz - fl(2*dot))
                unsigned int db = __float_as_uint(d);    // d > 0 always -> bits order == float order
                unsigned int jg = (unsigned)(n0v + wn * 64 + fj * 16 + rr);
                unsigned long long key = ((unsigned long long)db << 32) | jg;
                if (key < best) best = key;
            }
            atomicMin(&rowmin[rowl], best);
        }
    }
    __syncthreads();
    if (t < TM) atomicMin(&keys[m0 + t], rowmin[t]);
}

// ---------------- finalize idx ----------------
__global__ void vq_finalize_idx(const unsigned long long* __restrict__ keys,
                                float* __restrict__ out_idx) {
    int n = blockIdx.x * 256 + threadIdx.x;
    out_idx[n] = (float)(unsigned)(keys[n] & 0xFFFFFFFFull);
}

// ---------------- z_q (straight-through) + loss partials ----------------
__global__ void vq_zq_loss(const float* __restrict__ z, const float* __restrict__ cb,
                           const float* __restrict__ idxf, float* __restrict__ out0,
                           float* __restrict__ parts) {
    size_t i0 = ((size_t)blockIdx.x * 256 + threadIdx.x) * 8;
    int c   = (int)((i0 >> 13) & 255);
    int b   = (int)(i0 >> 21);
    int dhw = (int)(i0 & 8191);
    int nb  = b * DHW_ + dhw;
    float ls = 0.f;
    #pragma unroll
    for (int e = 0; e < 8; ++e) {
        int j = (int)idxf[nb + e];
        float zq = cb[(size_t)j * K_ + c];
        float zt = z[i0 + e];
        float diff = zq - zt;        // fl, matches ref
        out0[i0 + e] = zt + diff;    // fl(z_t + fl(z_q - z_t))
        ls += diff * diff;
    }
    __shared__ float red[256];
    red[threadIdx.x] = ls;
    __syncthreads();
    for (int s = 128; s > 0; s >>= 1) {
        if (threadIdx.x < (unsigned)s) red[threadIdx.x] += red[threadIdx.x + s];
        __syncthreads();
    }
    if (threadIdx.x == 0) parts[blockIdx.x] = red[0];
}

// ---------------- loss + perplexity ----------------
__global__ void vq_finalize_scalars(const float* __restrict__ parts,
                                    const float* __restrict__ idxf,
                                    float* __restrict__ out) {
    __shared__ int hist[NE_];
    __shared__ double dred[256];
    int t = threadIdx.x;
    for (int i = t; i < NE_; i += 256) hist[i] = 0;
    __syncthreads();
    for (int i = t; i < N_; i += 256) atomicAdd(&hist[(int)idxf[i]], 1);
    __syncthreads();
    double ent = 0.0;
    for (int i = t; i < NE_; i += 256) {
        float em = (float)hist[i] * (1.0f / 16384.0f);   // exact (pow2)
        float term = em * logf(em + 1e-10f);
        ent += (double)term;
    }
    dred[t] = ent;
    __syncthreads();
    for (int s = 128; s > 0; s >>= 1) {
        if (t < s) dred[t] += dred[t + s];
        __syncthreads();
    }
    double entr = 0.0;
    if (t == 0) entr = dred[0];
    __syncthreads();
    double ls = 0.0;
    for (int i = t; i < NLOSS_BLOCKS; i += 256) ls += (double)parts[i];
    dred[t] = ls;
    __syncthreads();
    for (int s = 128; s > 0; s >>= 1) {
        if (t < s) dred[t] += dred[t + s];
        __syncthreads();
    }
    if (t == 0) {
        double m = dred[0] / 4194304.0;
        float m1 = (float)m;
        out[LOSS_OFF] = m1 + 0.25f * m1;
        out[PERP_OFF] = (float)exp(-entr);
    }
}

// ---------------- fused zero-fill + one-hot write ----------------
// Writes the ENTIRE 512 MiB enc region (zeros + the 1.0 per row) in one pass.
// Must run after all scratch consumers (scratch lives in the enc tail).
__global__ void vq_write_enc(const float* __restrict__ idxf, float* __restrict__ enc) {
    int n = blockIdx.x;
    int j = (int)idxf[n];
    float4* row = (float4*)(enc + (size_t)n * NE_);
    int t = threadIdx.x;
    int jf = j >> 2;
    #pragma unroll
    for (int k = 0; k < 8; ++k) {
        int f = k * 256 + t;
        float4 v = {0.f, 0.f, 0.f, 0.f};
        if (f == jf) ((float*)&v)[j & 3] = 1.0f;
        row[f] = v;
    }
}

extern "C" void kernel_launch(void* const* d_in, const int* in_sizes, int n_in,
                              void* d_out, int out_size, void* d_ws, size_t ws_size,
                              hipStream_t stream) {
    const float* z  = (const float*)d_in[0];
    const float* cb = (const float*)d_in[1];
    float* out = (float*)d_out;

    char* encb = (char*)(out + ENC_OFF);
    _Float16* ZH = (_Float16*)(encb + SCR_ZH);
    _Float16* ZL = (_Float16*)(encb + SCR_ZL);
    _Float16* EH = (_Float16*)(encb + SCR_EH);
    _Float16* EL = (_Float16*)(encb + SCR_EL);
    float* zz = (float*)(encb + SCR_ZZ);
    unsigned long long* keys = (unsigned long long*)(encb + SCR_KEY);
    float* parts = (float*)(encb + SCR_PART);
    float* out_idx = out + IDX_OFF;
    float* enc = out + ENC_OFF;

    vq_split_z<<<256, 256, 0, stream>>>(z, ZH, ZL, zz);
    vq_split_e<<<128, 256, 0, stream>>>(cb, EH, EL, keys);
    vq_gemm_argmin<<<8192, 256, 0, stream>>>(ZH, ZL, EH, EL, zz, keys);
    vq_finalize_idx<<<64, 256, 0, stream>>>(keys, out_idx);
    vq_zq_loss<<<NLOSS_BLOCKS, 256, 0, stream>>>(z, cb, out_idx, out, parts);
    vq_finalize_scalars<<<1, 256, 0, stream>>>(parts, out_idx, out);
    vq_write_enc<<<N_, 256, 0, stream>>>(out_idx, enc);
}

// Round 3
// 434.928 us; speedup vs baseline: 1.2057x; 1.2057x over previous
//
#include <hip/hip_runtime.h>

typedef _Float16 half8 __attribute__((ext_vector_type(8)));
typedef float floatx4 __attribute__((ext_vector_type(4)));

#define DEVI __device__ __forceinline__
#define AS1 __attribute__((address_space(1)))
#define AS3 __attribute__((address_space(3)))
#define GLL(gp, lp) __builtin_amdgcn_global_load_lds((const AS1 void*)(gp), (AS3 void*)(lp), 16, 0, 0)
#define VM6 asm volatile("s_waitcnt vmcnt(6)" ::: "memory")
#define VM0 asm volatile("s_waitcnt vmcnt(0)" ::: "memory")
#define BAR __builtin_amdgcn_s_barrier()

namespace {
constexpr int C_   = 256;
constexpr int DHW_ = 8192;
constexpr int N_   = 16384;   // rows = B*D*H*W
constexpr int NE_  = 8192;    // codebook entries
constexpr int K_   = 256;     // embedding dim

constexpr size_t LOSS_OFF  = 4194304;
constexpr size_t PERP_OFF  = 4194305;
constexpr size_t ENC_OFF   = 4194306;
constexpr size_t ENC_N     = 134217728ull;
constexpr size_t IDX_OFF   = ENC_OFF + ENC_N;

// scratch offsets from 256B-aligned base inside enc-region tail
// (everything here is consumed before vq_write_enc overwrites it)
constexpr size_t SCR_ZH   = 480ull << 20;  // blocked 16384x256 f16 = 8 MiB
constexpr size_t SCR_ZL   = 488ull << 20;
constexpr size_t SCR_EH   = 496ull << 20;  // blocked 8192x256 f16 = 4 MiB
constexpr size_t SCR_EL   = 500ull << 20;
constexpr size_t SCR_ZZ   = 504ull << 20;  // 16384 f32
constexpr size_t SCR_KEY  = 505ull << 20;  // 16384 u64
constexpr size_t SCR_PART = 506ull << 20;  // loss partials f32
constexpr size_t SCR_HIST = 507ull << 20;  // 8192 i32

constexpr int NLOSS_BLOCKS = 2048;
}

// Blocked layouts (chosen so GEMM staging is contiguous 16B/lane and LDS
// ds_reads are conflict-free by construction):
//   A (Z): [tile=row>>8][chunk=k>>5][oct=(k>>3)&3][row&255][k&7]   tile = 128KB
//   B (E): [tile=row>>7][chunk     ][oct         ][row&127][k&7]   tile = 64KB

// ---------------- fused split: z and codebook -> blocked f16 splits ----------------
__global__ void vq_split(const float* __restrict__ z, const float* __restrict__ cb,
                         _Float16* __restrict__ ZHb, _Float16* __restrict__ ZLb,
                         _Float16* __restrict__ EHb, _Float16* __restrict__ ELb,
                         float* __restrict__ zz, unsigned long long* __restrict__ keys,
                         int* __restrict__ hist) {
    __shared__ float tile[64][260];
    int t = threadIdx.x;
    int j = t & 63, grp = t >> 6;
    if (blockIdx.x < 256) {
        // ---- Z path: rows n0..n0+63 ----
        int n0 = blockIdx.x * 64;
        int b  = n0 >> 13;
        int d0 = n0 & 8191;
        const float* zb = z + (size_t)b * (C_ * DHW_) + d0;
        for (int cc = 0; cc < 256; cc += 4) {
            int c = cc + grp;
            tile[j][c] = zb[(size_t)c * DHW_ + j];   // coalesced over j
        }
        __syncthreads();
        int tl = n0 >> 8, r0 = n0 & 255;
        #pragma unroll
        for (int it = 0; it < 8; ++it) {
            int rid = it * 4 + grp;                  // k-octet 0..31
            half8 h, l;
            #pragma unroll
            for (int e = 0; e < 8; ++e) {
                float v = tile[j][rid * 8 + e];
                _Float16 hh = (_Float16)v;
                h[e] = hh;
                l[e] = (_Float16)((v - (float)hh) * 2048.0f);  // residual scaled 2^11
            }
            size_t off = ((size_t)(tl * 8 + (rid >> 2))) * 8192
                       + (size_t)(rid & 3) * 2048 + (size_t)(r0 + j) * 8;
            *(half8*)(ZHb + off) = h;
            *(half8*)(ZLb + off) = l;
        }
        // zz (same math as the passing rounds; only binade matters)
        if (t < 64) {
            float tot[2];
            for (int h2 = 0; h2 < 2; ++h2) {
                float r8[8];
                #pragma unroll
                for (int k = 0; k < 8; ++k) { float x = tile[t][h2*128 + k]; r8[k] = x * x; }
                for (int i = 8; i < 128; i += 8) {
                    #pragma unroll
                    for (int k = 0; k < 8; ++k) { float x = tile[t][h2*128 + i + k]; r8[k] += x * x; }
                }
                tot[h2] = ((r8[0]+r8[1]) + (r8[2]+r8[3])) + ((r8[4]+r8[5]) + (r8[6]+r8[7]));
            }
            zz[n0 + t] = tot[0] + tot[1];
        }
        if (blockIdx.x < 64) keys[blockIdx.x * 256 + t] = ~0ull;
        else if (blockIdx.x < 96) hist[(blockIdx.x - 64) * 256 + t] = 0;
    } else {
        // ---- E path: codebook rows j0..j0+63, pre-scaled by 2^16 (exact) ----
        int j0 = (blockIdx.x - 256) * 64;
        for (int i = 0; i < 64; ++i)
            tile[i][t] = cb[(size_t)(j0 + i) * K_ + t] * 65536.0f;   // coalesced over t
        __syncthreads();
        int tl = j0 >> 7, r0 = j0 & 127;
        #pragma unroll
        for (int it = 0; it < 8; ++it) {
            int rid = it * 4 + grp;
            half8 h, l;
            #pragma unroll
            for (int e = 0; e < 8; ++e) {
                float v = tile[j][rid * 8 + e];
                _Float16 hh = (_Float16)v;
                h[e] = hh;
                l[e] = (_Float16)((v - (float)hh) * 2048.0f);
            }
            size_t off = ((size_t)(tl * 8 + (rid >> 2))) * 4096
                       + (size_t)(rid & 3) * 1024 + (size_t)(r0 + j) * 8;
            *(half8*)(EHb + off) = h;
            *(half8*)(ELb + off) = l;
        }
    }
}

// ---------------- GEMM + fused argmin ----------------
// TM=256, TN=128, KC=32, 8 chunks, 8 waves (4x2), wave tile 64x64.
// LDS buffer (48KB): ZH[4 oct][256 row][16B] | ZL | EH[4][128][16B] | EL
// 3 buffers, counted vmcnt(6) pipeline, one raw barrier per chunk.

DEVI void stage_chunk(const char* zh, const char* zl, const char* eh, const char* el,
                      char* b, int t, int c) {
    size_t ca = (size_t)c * 16384 + (size_t)t * 16;
    size_t ce = (size_t)c * 8192 + (size_t)t * 16;
    GLL(zh + ca,        b + t * 16);
    GLL(zh + ca + 8192, b + 8192 + t * 16);
    GLL(zl + ca,        b + 16384 + t * 16);
    GLL(zl + ca + 8192, b + 24576 + t * 16);
    GLL(eh + ce,        b + 32768 + t * 16);
    GLL(el + ce,        b + 40960 + t * 16);
}

DEVI void compute_chunk(const char* b, int wm, int wn, int g, int rr,
                        floatx4 (&acc_a)[4][4], floatx4 (&acc_b)[4][4]) {
    const char* Ab = b + g * 4096;            // ZH octet base (256 rows x 16B)
    const char* Bb = b + 32768 + g * 2048;    // EH octet base (128 rows x 16B)
    half8 azh[4], azl[4], beh[4], bel[4];
    #pragma unroll
    for (int f = 0; f < 4; ++f) {
        int row = wm * 64 + f * 16 + rr;
        azh[f] = *(const half8*)(Ab + row * 16);
        azl[f] = *(const half8*)(Ab + 16384 + row * 16);
        int col = wn * 64 + f * 16 + rr;
        beh[f] = *(const half8*)(Bb + col * 16);
        bel[f] = *(const half8*)(Bb + 8192 + col * 16);
    }
    __builtin_amdgcn_s_setprio(1);
    #pragma unroll
    for (int fi = 0; fi < 4; ++fi)
        #pragma unroll
        for (int fj = 0; fj < 4; ++fj) {
            acc_a[fi][fj] = __builtin_amdgcn_mfma_f32_16x16x32_f16(azh[fi], beh[fj], acc_a[fi][fj], 0, 0, 0);
            acc_b[fi][fj] = __builtin_amdgcn_mfma_f32_16x16x32_f16(azl[fi], beh[fj], acc_b[fi][fj], 0, 0, 0);
            acc_b[fi][fj] = __builtin_amdgcn_mfma_f32_16x16x32_f16(azh[fi], bel[fj], acc_b[fi][fj], 0, 0, 0);
        }
    __builtin_amdgcn_s_setprio(0);
}

__launch_bounds__(512, 2)
__global__ void vq_gemm_argmin(const _Float16* __restrict__ ZHb, const _Float16* __restrict__ ZLb,
                               const _Float16* __restrict__ EHb, const _Float16* __restrict__ ELb,
                               const float* __restrict__ zz,
                               unsigned long long* __restrict__ keys) {
    __shared__ _Float16 lds[3][24576];                // 3 x 48KB
    __shared__ unsigned long long rowmin[256];

    // XCD-locality: xcd owns bm in [8*xcd, 8*xcd+8), sweeps bn with 8-wide bm window
    int orig = blockIdx.x;
    int xcd = orig & 7;
    int loc = orig >> 3;              // 0..511
    int bm = xcd * 8 + (loc & 7);     // 0..63 (256-row Z tiles)
    int bn = loc >> 3;                // 0..63 (128-row E tiles)
    int m0 = bm * 256, n0v = bn * 128;

    int t = threadIdx.x;
    int lane = t & 63, wid = t >> 6;
    int wm = wid >> 1, wn = wid & 1;  // 4x2 waves of 64x64
    int g = lane >> 4, rr = lane & 15;

    const char* zh = (const char*)ZHb + (size_t)bm * 131072;
    const char* zl = (const char*)ZLb + (size_t)bm * 131072;
    const char* eh = (const char*)EHb + (size_t)bn * 65536;
    const char* el = (const char*)ELb + (size_t)bn * 65536;

    floatx4 acc_a[4][4], acc_b[4][4];
    #pragma unroll
    for (int i = 0; i < 4; ++i)
        #pragma unroll
        for (int jj = 0; jj < 4; ++jj) {
            acc_a[i][jj] = (floatx4){0.f, 0.f, 0.f, 0.f};
            acc_b[i][jj] = (floatx4){0.f, 0.f, 0.f, 0.f};
        }

    char* L0 = (char*)lds[0];
    char* L1 = (char*)lds[1];
    char* L2 = (char*)lds[2];

    stage_chunk(zh, zl, eh, el, L0, t, 0);
    stage_chunk(zh, zl, eh, el, L1, t, 1);
    VM6; BAR; stage_chunk(zh, zl, eh, el, L2, t, 2); compute_chunk(L0, wm, wn, g, rr, acc_a, acc_b);
    VM6; BAR; stage_chunk(zh, zl, eh, el, L0, t, 3); compute_chunk(L1, wm, wn, g, rr, acc_a, acc_b);
    VM6; BAR; stage_chunk(zh, zl, eh, el, L1, t, 4); compute_chunk(L2, wm, wn, g, rr, acc_a, acc_b);
    VM6; BAR; stage_chunk(zh, zl, eh, el, L2, t, 5); compute_chunk(L0, wm, wn, g, rr, acc_a, acc_b);
    VM6; BAR; stage_chunk(zh, zl, eh, el, L0, t, 6); compute_chunk(L1, wm, wn, g, rr, acc_a, acc_b);
    VM6; BAR; stage_chunk(zh, zl, eh, el, L1, t, 7); compute_chunk(L2, wm, wn, g, rr, acc_a, acc_b);
    VM6; BAR;                                        compute_chunk(L0, wm, wn, g, rr, acc_a, acc_b);
    VM0; BAR;                                        compute_chunk(L1, wm, wn, g, rr, acc_a, acc_b);

    if (t < 256) rowmin[t] = ~0ull;
    __syncthreads();

    constexpr float S_A = 1.0f / 65536.0f;       // 2^-16
    constexpr float S_B = 1.0f / 134217728.0f;   // 2^-27
    #pragma unroll
    for (int fi = 0; fi < 4; ++fi) {
        #pragma unroll
        for (int r = 0; r < 4; ++r) {
            int rowl = wm * 64 + fi * 16 + g * 4 + r;
            float zzv = zz[m0 + rowl];
            unsigned long long best = ~0ull;
            #pragma unroll
            for (int fj = 0; fj < 4; ++fj) {
                float dot = acc_a[fi][fj][r] * S_A + acc_b[fi][fj][r] * S_B;
                float d = zzv - 2.0f * dot;              // replicates ref fl(zz - fl(2*dot))
                unsigned int db = __float_as_uint(d);    // d > 0 -> bit order == float order
                unsigned int jg = (unsigned)(n0v + wn * 64 + fj * 16 + rr);
                unsigned long long key = ((unsigned long long)db << 32) | jg;
                if (key < best) best = key;
            }
            atomicMin(&rowmin[rowl], best);
        }
    }
    __syncthreads();
    if (t < 256) atomicMin(&keys[m0 + t], rowmin[t]);
}

// ---------------- finalize idx + histogram ----------------
__global__ void vq_finalize_idx(const unsigned long long* __restrict__ keys,
                                float* __restrict__ out_idx, int* __restrict__ hist) {
    int n = blockIdx.x * 256 + threadIdx.x;
    unsigned j = (unsigned)(keys[n] & 0xFFFFFFFFull);
    out_idx[n] = (float)j;
    atomicAdd(&hist[j], 1);
}

// ---------------- z_q (straight-through) + loss partials ----------------
__global__ void vq_zq_loss(const float* __restrict__ z, const float* __restrict__ cb,
                           const float* __restrict__ idxf, float* __restrict__ out0,
                           float* __restrict__ parts) {
    size_t i0 = ((size_t)blockIdx.x * 256 + threadIdx.x) * 8;
    int c   = (int)((i0 >> 13) & 255);
    int b   = (int)(i0 >> 21);
    int dhw = (int)(i0 & 8191);
    int nb  = b * DHW_ + dhw;
    float ls = 0.f;
    #pragma unroll
    for (int e = 0; e < 8; ++e) {
        int j = (int)idxf[nb + e];
        float zq = cb[(size_t)j * K_ + c];
        float zt = z[i0 + e];
        float diff = zq - zt;        // fl, matches ref
        out0[i0 + e] = zt + diff;    // fl(z_t + fl(z_q - z_t))
        ls += diff * diff;
    }
    __shared__ float red[256];
    red[threadIdx.x] = ls;
    __syncthreads();
    for (int s = 128; s > 0; s >>= 1) {
        if (threadIdx.x < (unsigned)s) red[threadIdx.x] += red[threadIdx.x + s];
        __syncthreads();
    }
    if (threadIdx.x == 0) parts[blockIdx.x] = red[0];
}

// ---------------- loss + perplexity ----------------
__global__ void vq_finalize_scalars(const float* __restrict__ parts,
                                    const int* __restrict__ hist,
                                    float* __restrict__ out) {
    __shared__ double dred[256];
    int t = threadIdx.x;
    double ent = 0.0;
    for (int i = t; i < NE_; i += 256) {
        float em = (float)hist[i] * (1.0f / 16384.0f);   // exact (pow2)
        float term = em * logf(em + 1e-10f);
        ent += (double)term;
    }
    dred[t] = ent;
    __syncthreads();
    for (int s = 128; s > 0; s >>= 1) {
        if (t < s) dred[t] += dred[t + s];
        __syncthreads();
    }
    double entr = 0.0;
    if (t == 0) entr = dred[0];
    __syncthreads();
    double ls = 0.0;
    for (int i = t; i < NLOSS_BLOCKS; i += 256) ls += (double)parts[i];
    dred[t] = ls;
    __syncthreads();
    for (int s = 128; s > 0; s >>= 1) {
        if (t < s) dred[t] += dred[t + s];
        __syncthreads();
    }
    if (t == 0) {
        double m = dred[0] / 4194304.0;
        float m1 = (float)m;
        out[LOSS_OFF] = m1 + 0.25f * m1;
        out[PERP_OFF] = (float)exp(-entr);
    }
}

// ---------------- fused zero-fill + one-hot write (aligned float2) ----------------
__global__ void vq_write_enc(const float* __restrict__ idxf, float* __restrict__ enc) {
    int n = blockIdx.x;
    int j = (int)idxf[n];
    float2* row = (float2*)(enc + (size_t)n * NE_);
    int t = threadIdx.x;
    int jf = j >> 1;
    #pragma unroll
    for (int k = 0; k < 16; ++k) {
        int f = k * 256 + t;
        float2 v = {0.f, 0.f};
        if (f == jf) ((float*)&v)[j & 1] = 1.0f;
        row[f] = v;
    }
}

extern "C" void kernel_launch(void* const* d_in, const int* in_sizes, int n_in,
                              void* d_out, int out_size, void* d_ws, size_t ws_size,
                              hipStream_t stream) {
    const float* z  = (const float*)d_in[0];
    const float* cb = (const float*)d_in[1];
    float* out = (float*)d_out;

    // 256B-aligned scratch base inside the enc-region tail
    char* scr = (char*)(((uintptr_t)(out + ENC_OFF) + 255) & ~(uintptr_t)255);
    _Float16* ZHb = (_Float16*)(scr + SCR_ZH);
    _Float16* ZLb = (_Float16*)(scr + SCR_ZL);
    _Float16* EHb = (_Float16*)(scr + SCR_EH);
    _Float16* ELb = (_Float16*)(scr + SCR_EL);
    float* zz = (float*)(scr + SCR_ZZ);
    unsigned long long* keys = (unsigned long long*)(scr + SCR_KEY);
    float* parts = (float*)(scr + SCR_PART);
    int* hist = (int*)(scr + SCR_HIST);
    float* out_idx = out + IDX_OFF;
    float* enc = out + ENC_OFF;

    vq_split<<<384, 256, 0, stream>>>(z, cb, ZHb, ZLb, EHb, ELb, zz, keys, hist);
    vq_gemm_argmin<<<4096, 512, 0, stream>>>(ZHb, ZLb, EHb, ELb, zz, keys);
    vq_finalize_idx<<<64, 256, 0, stream>>>(keys, out_idx, hist);
    vq_zq_loss<<<NLOSS_BLOCKS, 256, 0, stream>>>(z, cb, out_idx, out, parts);
    vq_finalize_scalars<<<1, 256, 0, stream>>>(parts, hist, out);
    vq_write_enc<<<N_, 256, 0, stream>>>(out_idx, enc);
}

// Round 4
// 389.884 us; speedup vs baseline: 1.3450x; 1.1155x over previous
//
#include <hip/hip_runtime.h>

typedef _Float16 half8 __attribute__((ext_vector_type(8)));
typedef float floatx4 __attribute__((ext_vector_type(4)));

#define DEVI __device__ __forceinline__
#define AS1 __attribute__((address_space(1)))
#define AS3 __attribute__((address_space(3)))
#define GLL(gp, lp) __builtin_amdgcn_global_load_lds((const AS1 void*)(gp), (AS3 void*)(lp), 16, 0, 0)
#define VM8 asm volatile("s_waitcnt vmcnt(8)" ::: "memory")
#define VM0 asm volatile("s_waitcnt vmcnt(0)" ::: "memory")
#define BAR __builtin_amdgcn_s_barrier()

namespace {
constexpr int C_   = 256;
constexpr int DHW_ = 8192;
constexpr int N_   = 16384;   // rows = B*D*H*W
constexpr int NE_  = 8192;    // codebook entries
constexpr int K_   = 256;     // embedding dim

constexpr size_t LOSS_OFF  = 4194304;
constexpr size_t PERP_OFF  = 4194305;
constexpr size_t ENC_OFF   = 4194306;
constexpr size_t ENC_N     = 134217728ull;
constexpr size_t IDX_OFF   = ENC_OFF + ENC_N;

// scratch offsets from 256B-aligned base inside enc-region tail
// (everything here is consumed before vq_write_enc overwrites it)
constexpr size_t SCR_ZH   = 480ull << 20;  // blocked 16384x256 f16 = 8 MiB
constexpr size_t SCR_ZL   = 488ull << 20;
constexpr size_t SCR_EH   = 496ull << 20;  // blocked 8192x256 f16 = 4 MiB
constexpr size_t SCR_EL   = 500ull << 20;
constexpr size_t SCR_ZZ   = 504ull << 20;  // 16384 f32
constexpr size_t SCR_KEY  = 505ull << 20;  // 16384 u64
constexpr size_t SCR_PART = 506ull << 20;  // loss partials f32
constexpr size_t SCR_HIST = 507ull << 20;  // 8192 i32

constexpr int NLOSS_BLOCKS = 2048;
}

// Blocked layouts (GEMM staging contiguous 16B/lane; LDS conflict-free):
//   A (Z): bytes = tile256*131072 + chunk*16384 + oct*4096 + row*16   (row in tile)
//   B (E): bytes = tile128*65536  + chunk*8192  + oct*2048 + row*16

// ---------------- fused split: z and codebook -> blocked f16 splits ----------------
__global__ void vq_split(const float* __restrict__ z, const float* __restrict__ cb,
                         _Float16* __restrict__ ZHb, _Float16* __restrict__ ZLb,
                         _Float16* __restrict__ EHb, _Float16* __restrict__ ELb,
                         float* __restrict__ zz, unsigned long long* __restrict__ keys,
                         int* __restrict__ hist) {
    __shared__ float tile[64][260];
    int t = threadIdx.x;
    int j = t & 63, grp = t >> 6;
    if (blockIdx.x < 256) {
        // ---- Z path: rows n0..n0+63 ----
        int n0 = blockIdx.x * 64;
        int b  = n0 >> 13;
        int d0 = n0 & 8191;
        const float* zb = z + (size_t)b * (C_ * DHW_) + d0;
        for (int cc = 0; cc < 256; cc += 4) {
            int c = cc + grp;
            tile[j][c] = zb[(size_t)c * DHW_ + j];   // coalesced over j
        }
        __syncthreads();
        int tl = n0 >> 8, r0 = n0 & 255;
        #pragma unroll
        for (int it = 0; it < 8; ++it) {
            int rid = it * 4 + grp;                  // k-octet 0..31
            half8 h, l;
            #pragma unroll
            for (int e = 0; e < 8; ++e) {
                float v = tile[j][rid * 8 + e];
                _Float16 hh = (_Float16)v;
                h[e] = hh;
                l[e] = (_Float16)((v - (float)hh) * 2048.0f);  // residual scaled 2^11
            }
            size_t off = ((size_t)(tl * 8 + (rid >> 2))) * 8192
                       + (size_t)(rid & 3) * 2048 + (size_t)(r0 + j) * 8;
            *(half8*)(ZHb + off) = h;
            *(half8*)(ZLb + off) = l;
        }
        // zz (same math as the passing rounds; only binade matters)
        if (t < 64) {
            float tot[2];
            for (int h2 = 0; h2 < 2; ++h2) {
                float r8[8];
                #pragma unroll
                for (int k = 0; k < 8; ++k) { float x = tile[t][h2*128 + k]; r8[k] = x * x; }
                for (int i = 8; i < 128; i += 8) {
                    #pragma unroll
                    for (int k = 0; k < 8; ++k) { float x = tile[t][h2*128 + i + k]; r8[k] += x * x; }
                }
                tot[h2] = ((r8[0]+r8[1]) + (r8[2]+r8[3])) + ((r8[4]+r8[5]) + (r8[6]+r8[7]));
            }
            zz[n0 + t] = tot[0] + tot[1];
        }
        if (blockIdx.x < 64) keys[blockIdx.x * 256 + t] = ~0ull;
        else if (blockIdx.x < 96) hist[(blockIdx.x - 64) * 256 + t] = 0;
    } else {
        // ---- E path: codebook rows j0..j0+63, pre-scaled by 2^16 (exact) ----
        int j0 = (blockIdx.x - 256) * 64;
        for (int i = 0; i < 64; ++i)
            tile[i][t] = cb[(size_t)(j0 + i) * K_ + t] * 65536.0f;   // coalesced over t
        __syncthreads();
        int tl = j0 >> 7, r0 = j0 & 127;
        #pragma unroll
        for (int it = 0; it < 8; ++it) {
            int rid = it * 4 + grp;
            half8 h, l;
            #pragma unroll
            for (int e = 0; e < 8; ++e) {
                float v = tile[j][rid * 8 + e];
                _Float16 hh = (_Float16)v;
                h[e] = hh;
                l[e] = (_Float16)((v - (float)hh) * 2048.0f);
            }
            size_t off = ((size_t)(tl * 8 + (rid >> 2))) * 4096
                       + (size_t)(rid & 3) * 1024 + (size_t)(r0 + j) * 8;
            *(half8*)(EHb + off) = h;
            *(half8*)(ELb + off) = l;
        }
    }
}

// ---------------- GEMM + fused argmin ----------------
// TM=TN=128, KC=32, 8 chunks, 4 waves (2x2), wave tile 64x64.
// LDS buffer (32KB): ZH[4oct][128][16B] | ZL | EH | EL.  2 buffers -> 2 blocks/CU.
// Counted vmcnt(8): stage(c+2) issued after post-compute barrier, drained one
// chunk later; never vmcnt(0) in the main loop.

DEVI void stage_chunk(const char* zh, const char* zl, const char* eh, const char* el,
                      char* b, int t, int c) {
    #pragma unroll
    for (int i = 0; i < 2; ++i) {
        int f = i * 256 + t;                       // 0..511 = oct*128 + row
        int ao = (f >> 7) * 4096 + (f & 127) * 16; // A src offset within chunk
        int eo = (f >> 7) * 2048 + (f & 127) * 16; // B src offset within chunk
        GLL(zh + (size_t)c * 16384 + ao, b + f * 16);
        GLL(zl + (size_t)c * 16384 + ao, b + 8192 + f * 16);
        GLL(eh + (size_t)c * 8192 + eo, b + 16384 + f * 16);
        GLL(el + (size_t)c * 8192 + eo, b + 24576 + f * 16);
    }
}

DEVI void compute_chunk(const char* b, int wm, int wn, int g, int rr,
                        floatx4 (&acc_a)[4][4], floatx4 (&acc_b)[4][4]) {
    const char* Ab = b + g * 2048;            // ZH octet base (128 rows x 16B)
    const char* Bb = b + 16384 + g * 2048;    // EH octet base
    half8 azh[4], azl[4], beh[4], bel[4];
    #pragma unroll
    for (int f = 0; f < 4; ++f) {
        int row = wm * 64 + f * 16 + rr;
        azh[f] = *(const half8*)(Ab + row * 16);
        azl[f] = *(const half8*)(Ab + 8192 + row * 16);
        int col = wn * 64 + f * 16 + rr;
        beh[f] = *(const half8*)(Bb + col * 16);
        bel[f] = *(const half8*)(Bb + 8192 + col * 16);
    }
    __builtin_amdgcn_s_setprio(1);
    #pragma unroll
    for (int fi = 0; fi < 4; ++fi)
        #pragma unroll
        for (int fj = 0; fj < 4; ++fj) {
            acc_a[fi][fj] = __builtin_amdgcn_mfma_f32_16x16x32_f16(azh[fi], beh[fj], acc_a[fi][fj], 0, 0, 0);
            acc_b[fi][fj] = __builtin_amdgcn_mfma_f32_16x16x32_f16(azl[fi], beh[fj], acc_b[fi][fj], 0, 0, 0);
            acc_b[fi][fj] = __builtin_amdgcn_mfma_f32_16x16x32_f16(azh[fi], bel[fj], acc_b[fi][fj], 0, 0, 0);
        }
    __builtin_amdgcn_s_setprio(0);
}

__launch_bounds__(256, 2)
__global__ void vq_gemm_argmin(const _Float16* __restrict__ ZHb, const _Float16* __restrict__ ZLb,
                               const _Float16* __restrict__ EHb, const _Float16* __restrict__ ELb,
                               const float* __restrict__ zz,
                               unsigned long long* __restrict__ keys) {
    __shared__ _Float16 lds[2][16384];                // 2 x 32KB
    __shared__ unsigned long long rowmin[128];

    // XCD-locality: xcd owns bm in [16x, 16x+16), sweeps bn
    int orig = blockIdx.x;
    int xcd = orig & 7;
    int loc = orig >> 3;                 // 0..1023
    int bm = xcd * 16 + (loc & 15);      // 0..127 (128-row Z slices)
    int bn = loc >> 4;                   // 0..63  (128-row E tiles)
    int m0 = bm * 128, n0v = bn * 128;

    int t = threadIdx.x;
    int lane = t & 63, wid = t >> 6;
    int wm = wid >> 1, wn = wid & 1;     // 2x2 waves of 64x64
    int g = lane >> 4, rr = lane & 15;

    // A slice = half of a 256-row blocked tile
    const char* zh = (const char*)ZHb + (size_t)(bm >> 1) * 131072 + (size_t)(bm & 1) * 2048;
    const char* zl = (const char*)ZLb + (size_t)(bm >> 1) * 131072 + (size_t)(bm & 1) * 2048;
    const char* eh = (const char*)EHb + (size_t)bn * 65536;
    const char* el = (const char*)ELb + (size_t)bn * 65536;

    floatx4 acc_a[4][4], acc_b[4][4];
    #pragma unroll
    for (int i = 0; i < 4; ++i)
        #pragma unroll
        for (int jj = 0; jj < 4; ++jj) {
            acc_a[i][jj] = (floatx4){0.f, 0.f, 0.f, 0.f};
            acc_b[i][jj] = (floatx4){0.f, 0.f, 0.f, 0.f};
        }

    char* L0 = (char*)lds[0];
    char* L1 = (char*)lds[1];

    stage_chunk(zh, zl, eh, el, L0, t, 0);
    stage_chunk(zh, zl, eh, el, L1, t, 1);
    VM8; BAR; compute_chunk(L0, wm, wn, g, rr, acc_a, acc_b);
    BAR; stage_chunk(zh, zl, eh, el, L0, t, 2);
    VM8; BAR; compute_chunk(L1, wm, wn, g, rr, acc_a, acc_b);
    BAR; stage_chunk(zh, zl, eh, el, L1, t, 3);
    VM8; BAR; compute_chunk(L0, wm, wn, g, rr, acc_a, acc_b);
    BAR; stage_chunk(zh, zl, eh, el, L0, t, 4);
    VM8; BAR; compute_chunk(L1, wm, wn, g, rr, acc_a, acc_b);
    BAR; stage_chunk(zh, zl, eh, el, L1, t, 5);
    VM8; BAR; compute_chunk(L0, wm, wn, g, rr, acc_a, acc_b);
    BAR; stage_chunk(zh, zl, eh, el, L0, t, 6);
    VM8; BAR; compute_chunk(L1, wm, wn, g, rr, acc_a, acc_b);
    BAR; stage_chunk(zh, zl, eh, el, L1, t, 7);
    VM8; BAR; compute_chunk(L0, wm, wn, g, rr, acc_a, acc_b);
    VM0; BAR; compute_chunk(L1, wm, wn, g, rr, acc_a, acc_b);

    if (t < 128) rowmin[t] = ~0ull;
    __syncthreads();

    constexpr float S_A = 1.0f / 65536.0f;       // 2^-16
    constexpr float S_B = 1.0f / 134217728.0f;   // 2^-27
    #pragma unroll
    for (int fi = 0; fi < 4; ++fi) {
        #pragma unroll
        for (int r = 0; r < 4; ++r) {
            int rowl = wm * 64 + fi * 16 + g * 4 + r;
            float zzv = zz[m0 + rowl];
            unsigned long long best = ~0ull;
            #pragma unroll
            for (int fj = 0; fj < 4; ++fj) {
                float dot = acc_a[fi][fj][r] * S_A + acc_b[fi][fj][r] * S_B;
                float d = zzv - 2.0f * dot;              // replicates ref fl(zz - fl(2*dot))
                unsigned int db = __float_as_uint(d);    // d > 0 -> bit order == float order
                unsigned int jg = (unsigned)(n0v + wn * 64 + fj * 16 + rr);
                unsigned long long key = ((unsigned long long)db << 32) | jg;
                if (key < best) best = key;
            }
            // cross-lane min over the 16 rr-lanes (same rowl) -> conflict-free atomic
            #pragma unroll
            for (int s = 1; s < 16; s <<= 1) {
                unsigned long long o = __shfl_xor(best, s, 64);
                if (o < best) best = o;
            }
            if (rr == 0) atomicMin(&rowmin[rowl], best);
        }
    }
    __syncthreads();
    if (t < 128) atomicMin(&keys[m0 + t], rowmin[t]);
}

// ---------------- finalize idx + histogram ----------------
__global__ void vq_finalize_idx(const unsigned long long* __restrict__ keys,
                                float* __restrict__ out_idx, int* __restrict__ hist) {
    int n = blockIdx.x * 256 + threadIdx.x;
    unsigned j = (unsigned)(keys[n] & 0xFFFFFFFFull);
    out_idx[n] = (float)j;
    atomicAdd(&hist[j], 1);
}

// ---------------- z_q (straight-through) + loss partials ----------------
__global__ void vq_zq_loss(const float* __restrict__ z, const float* __restrict__ cb,
                           const float* __restrict__ idxf, float* __restrict__ out0,
                           float* __restrict__ parts) {
    size_t i0 = ((size_t)blockIdx.x * 256 + threadIdx.x) * 8;
    int c   = (int)((i0 >> 13) & 255);
    int b   = (int)(i0 >> 21);
    int dhw = (int)(i0 & 8191);
    int nb  = b * DHW_ + dhw;
    float ls = 0.f;
    #pragma unroll
    for (int e = 0; e < 8; ++e) {
        int j = (int)idxf[nb + e];
        float zq = cb[(size_t)j * K_ + c];
        float zt = z[i0 + e];
        float diff = zq - zt;        // fl, matches ref
        out0[i0 + e] = zt + diff;    // fl(z_t + fl(z_q - z_t))
        ls += diff * diff;
    }
    __shared__ float red[256];
    red[threadIdx.x] = ls;
    __syncthreads();
    for (int s = 128; s > 0; s >>= 1) {
        if (threadIdx.x < (unsigned)s) red[threadIdx.x] += red[threadIdx.x + s];
        __syncthreads();
    }
    if (threadIdx.x == 0) parts[blockIdx.x] = red[0];
}

// ---------------- loss + perplexity ----------------
__global__ void vq_finalize_scalars(const float* __restrict__ parts,
                                    const int* __restrict__ hist,
                                    float* __restrict__ out) {
    __shared__ double dred[256];
    int t = threadIdx.x;
    double ent = 0.0;
    for (int i = t; i < NE_; i += 256) {
        float em = (float)hist[i] * (1.0f / 16384.0f);   // exact (pow2)
        float term = em * logf(em + 1e-10f);
        ent += (double)term;
    }
    dred[t] = ent;
    __syncthreads();
    for (int s = 128; s > 0; s >>= 1) {
        if (t < s) dred[t] += dred[t + s];
        __syncthreads();
    }
    double entr = 0.0;
    if (t == 0) entr = dred[0];
    __syncthreads();
    double ls = 0.0;
    for (int i = t; i < NLOSS_BLOCKS; i += 256) ls += (double)parts[i];
    dred[t] = ls;
    __syncthreads();
    for (int s = 128; s > 0; s >>= 1) {
        if (t < s) dred[t] += dred[t + s];
        __syncthreads();
    }
    if (t == 0) {
        double m = dred[0] / 4194304.0;
        float m1 = (float)m;
        out[LOSS_OFF] = m1 + 0.25f * m1;
        out[PERP_OFF] = (float)exp(-entr);
    }
}

// ---------------- fused zero-fill + one-hot write ----------------
// Row base is 8 mod 16 -> head float2 (cols 0-1), 2047 aligned float4
// (cols 2..8189), tail float2 (cols 8190-8191).
__global__ void vq_write_enc(const float* __restrict__ idxf, float* __restrict__ enc) {
    int n = blockIdx.x;
    int j = (int)idxf[n];
    float* row = enc + (size_t)n * NE_;
    int t = threadIdx.x;
    #pragma unroll
    for (int k = 0; k < 8; ++k) {
        int f = k * 256 + t;                 // 0..2047
        if (f < 2047) {
            int c0 = 2 + f * 4;
            float4 v = {0.f, 0.f, 0.f, 0.f};
            int d = j - c0;
            if ((unsigned)d < 4u) ((float*)&v)[d] = 1.0f;
            *(float4*)(row + c0) = v;
        } else {
            float2 h = {0.f, 0.f}, tl = {0.f, 0.f};
            if (j < 2) ((float*)&h)[j] = 1.0f;
            if (j >= 8190) ((float*)&tl)[j - 8190] = 1.0f;
            *(float2*)(row) = h;
            *(float2*)(row + 8190) = tl;
        }
    }
}

extern "C" void kernel_launch(void* const* d_in, const int* in_sizes, int n_in,
                              void* d_out, int out_size, void* d_ws, size_t ws_size,
                              hipStream_t stream) {
    const float* z  = (const float*)d_in[0];
    const float* cb = (const float*)d_in[1];
    float* out = (float*)d_out;

    // 256B-aligned scratch base inside the enc-region tail
    char* scr = (char*)(((uintptr_t)(out + ENC_OFF) + 255) & ~(uintptr_t)255);
    _Float16* ZHb = (_Float16*)(scr + SCR_ZH);
    _Float16* ZLb = (_Float16*)(scr + SCR_ZL);
    _Float16* EHb = (_Float16*)(scr + SCR_EH);
    _Float16* ELb = (_Float16*)(scr + SCR_EL);
    float* zz = (float*)(scr + SCR_ZZ);
    unsigned long long* keys = (unsigned long long*)(scr + SCR_KEY);
    float* parts = (float*)(scr + SCR_PART);
    int* hist = (int*)(scr + SCR_HIST);
    float* out_idx = out + IDX_OFF;
    float* enc = out + ENC_OFF;

    vq_split<<<384, 256, 0, stream>>>(z, cb, ZHb, ZLb, EHb, ELb, zz, keys, hist);
    vq_gemm_argmin<<<8192, 256, 0, stream>>>(ZHb, ZLb, EHb, ELb, zz, keys);
    vq_finalize_idx<<<64, 256, 0, stream>>>(keys, out_idx, hist);
    vq_zq_loss<<<NLOSS_BLOCKS, 256, 0, stream>>>(z, cb, out_idx, out, parts);
    vq_finalize_scalars<<<1, 256, 0, stream>>>(parts, hist, out);
    vq_write_enc<<<N_, 256, 0, stream>>>(out_idx, enc);
}

// Round 6
// 294.529 us; speedup vs baseline: 1.7804x; 1.3238x over previous
//
#include <hip/hip_runtime.h>

typedef _Float16 half8 __attribute__((ext_vector_type(8)));
typedef float floatx4 __attribute__((ext_vector_type(4)));

#define DEVI __device__ __forceinline__
#define AS1 __attribute__((address_space(1)))
#define AS3 __attribute__((address_space(3)))
#define GLL(gp, lp) __builtin_amdgcn_global_load_lds((const AS1 void*)(gp), (AS3 void*)(lp), 16, 0, 0)
#define VM0 asm volatile("s_waitcnt vmcnt(0)" ::: "memory")
#define BAR __builtin_amdgcn_s_barrier()

namespace {
constexpr int C_   = 256;
constexpr int DHW_ = 8192;
constexpr int N_   = 16384;   // rows = B*D*H*W
constexpr int NE_  = 8192;    // codebook entries
constexpr int K_   = 256;     // embedding dim

constexpr size_t LOSS_OFF  = 4194304;
constexpr size_t PERP_OFF  = 4194305;
constexpr size_t ENC_OFF   = 4194306;
constexpr size_t ENC_N     = 134217728ull;
constexpr size_t IDX_OFF   = ENC_OFF + ENC_N;

// scratch offsets from 256B-aligned base inside enc-region tail
// (everything here is consumed before vq_zero_tail wipes it)
constexpr size_t SCR_ZH   = 480ull << 20;  // blocked 16384x256 f16 = 8 MiB
constexpr size_t SCR_ZL   = 488ull << 20;
constexpr size_t SCR_EH   = 496ull << 20;  // blocked 8192x256 f16 = 4 MiB
constexpr size_t SCR_EL   = 500ull << 20;
constexpr size_t SCR_ZZ   = 504ull << 20;  // 16384 f32
constexpr size_t SCR_KEY  = 505ull << 20;  // 16384 u64
constexpr size_t SCR_PART = 506ull << 20;  // loss partials f32
constexpr size_t SCR_HIST = 507ull << 20;  // 8192 i32

constexpr int NLOSS_BLOCKS = 2048;

// enc zero-fill split: gemm blocks NT-store [8, 8+8192*61440); tail kernel does the rest.
constexpr size_t ZFILL_PER_BLK = 61440;                       // 15 x 4KB rounds
constexpr size_t TAIL_START    = 8 + 8192ull * ZFILL_PER_BLK; // 503316488
constexpr size_t TAIL_F4       = (536870904ull - TAIL_START) / 16;  // 2097151
}

// Blocked layouts (GEMM staging contiguous 16B/lane; LDS conflict-free):
//   A (Z): bytes = tile256*131072 + chunk*16384 + oct*4096 + row*16   (row in tile)
//   B (E): bytes = tile128*65536  + chunk*8192  + oct*2048 + row*16

// ---------------- fused split: z and codebook -> blocked f16 splits ----------------
__global__ void vq_split(const float* __restrict__ z, const float* __restrict__ cb,
                         _Float16* __restrict__ ZHb, _Float16* __restrict__ ZLb,
                         _Float16* __restrict__ EHb, _Float16* __restrict__ ELb,
                         float* __restrict__ zz, unsigned long long* __restrict__ keys,
                         int* __restrict__ hist) {
    __shared__ float tile[64][260];
    int t = threadIdx.x;
    int j = t & 63, grp = t >> 6;
    if (blockIdx.x < 256) {
        // ---- Z path: rows n0..n0+63 ----
        int n0 = blockIdx.x * 64;
        int b  = n0 >> 13;
        int d0 = n0 & 8191;
        const float* zb = z + (size_t)b * (C_ * DHW_) + d0;
        for (int cc = 0; cc < 256; cc += 4) {
            int c = cc + grp;
            tile[j][c] = zb[(size_t)c * DHW_ + j];   // coalesced over j
        }
        __syncthreads();
        int tl = n0 >> 8, r0 = n0 & 255;
        #pragma unroll
        for (int it = 0; it < 8; ++it) {
            int rid = it * 4 + grp;                  // k-octet 0..31
            half8 h, l;
            #pragma unroll
            for (int e = 0; e < 8; ++e) {
                float v = tile[j][rid * 8 + e];
                _Float16 hh = (_Float16)v;
                h[e] = hh;
                l[e] = (_Float16)((v - (float)hh) * 2048.0f);  // residual scaled 2^11
            }
            size_t off = ((size_t)(tl * 8 + (rid >> 2))) * 8192
                       + (size_t)(rid & 3) * 2048 + (size_t)(r0 + j) * 8;
            *(half8*)(ZHb + off) = h;
            *(half8*)(ZLb + off) = l;
        }
        // zz (same math as the passing rounds; only binade matters)
        if (t < 64) {
            float tot[2];
            for (int h2 = 0; h2 < 2; ++h2) {
                float r8[8];
                #pragma unroll
                for (int k = 0; k < 8; ++k) { float x = tile[t][h2*128 + k]; r8[k] = x * x; }
                for (int i = 8; i < 128; i += 8) {
                    #pragma unroll
                    for (int k = 0; k < 8; ++k) { float x = tile[t][h2*128 + i + k]; r8[k] += x * x; }
                }
                tot[h2] = ((r8[0]+r8[1]) + (r8[2]+r8[3])) + ((r8[4]+r8[5]) + (r8[6]+r8[7]));
            }
            zz[n0 + t] = tot[0] + tot[1];
        }
        if (blockIdx.x < 64) keys[blockIdx.x * 256 + t] = ~0ull;
        else if (blockIdx.x < 96) hist[(blockIdx.x - 64) * 256 + t] = 0;
    } else {
        // ---- E path: codebook rows j0..j0+63, pre-scaled by 2^16 (exact) ----
        int j0 = (blockIdx.x - 256) * 64;
        for (int i = 0; i < 64; ++i)
            tile[i][t] = cb[(size_t)(j0 + i) * K_ + t] * 65536.0f;   // coalesced over t
        __syncthreads();
        int tl = j0 >> 7, r0 = j0 & 127;
        #pragma unroll
        for (int it = 0; it < 8; ++it) {
            int rid = it * 4 + grp;
            half8 h, l;
            #pragma unroll
            for (int e = 0; e < 8; ++e) {
                float v = tile[j][rid * 8 + e];
                _Float16 hh = (_Float16)v;
                h[e] = hh;
                l[e] = (_Float16)((v - (float)hh) * 2048.0f);
            }
            size_t off = ((size_t)(tl * 8 + (rid >> 2))) * 4096
                       + (size_t)(rid & 3) * 1024 + (size_t)(r0 + j) * 8;
            *(half8*)(EHb + off) = h;
            *(half8*)(ELb + off) = l;
        }
    }
}

// ---------------- GEMM + fused argmin + enc zero-fill absorption ----------------
// TM=TN=128, KC=32, 8 chunks, 4 waves (2x2), 2 buffers x 32KB -> 2 blocks/CU.
// Schedule per chunk: stage(next buf) ; NT-zero 8KB of enc ; compute(cur) ; VM0 ; BAR.
// VM0 waits on loads/stores that had a full ~900-cyc compute phase to retire.

DEVI void stage_chunk(const char* zh, const char* zl, const char* eh, const char* el,
                      char* b, int t, int c) {
    #pragma unroll
    for (int i = 0; i < 2; ++i) {
        int f = i * 256 + t;                       // 0..511 = oct*128 + row
        int ao = (f >> 7) * 4096 + (f & 127) * 16; // A src offset within chunk
        int eo = (f >> 7) * 2048 + (f & 127) * 16; // B src offset within chunk
        GLL(zh + (size_t)c * 16384 + ao, b + f * 16);
        GLL(zl + (size_t)c * 16384 + ao, b + 8192 + f * 16);
        GLL(eh + (size_t)c * 8192 + eo, b + 16384 + f * 16);
        GLL(el + (size_t)c * 8192 + eo, b + 24576 + f * 16);
    }
}

DEVI void zfill2(char* zb, int t, int r0) {
    floatx4 z4 = {0.f, 0.f, 0.f, 0.f};
    __builtin_nontemporal_store(z4, (floatx4*)(zb + (size_t)r0 * 4096 + t * 16));
    __builtin_nontemporal_store(z4, (floatx4*)(zb + (size_t)(r0 + 1) * 4096 + t * 16));
}

DEVI void compute_chunk(const char* b, int wm, int wn, int g, int rr,
                        floatx4 (&acc_a)[4][4], floatx4 (&acc_b)[4][4]) {
    const char* Ab = b + g * 2048;            // ZH octet base (128 rows x 16B)
    const char* Bb = b + 16384 + g * 2048;    // EH octet base
    half8 azh[4], azl[4], beh[4], bel[4];
    #pragma unroll
    for (int f = 0; f < 4; ++f) {
        int row = wm * 64 + f * 16 + rr;
        azh[f] = *(const half8*)(Ab + row * 16);
        azl[f] = *(const half8*)(Ab + 8192 + row * 16);
        int col = wn * 64 + f * 16 + rr;
        beh[f] = *(const half8*)(Bb + col * 16);
        bel[f] = *(const half8*)(Bb + 8192 + col * 16);
    }
    __builtin_amdgcn_s_setprio(1);
    #pragma unroll
    for (int fi = 0; fi < 4; ++fi)
        #pragma unroll
        for (int fj = 0; fj < 4; ++fj) {
            acc_a[fi][fj] = __builtin_amdgcn_mfma_f32_16x16x32_f16(azh[fi], beh[fj], acc_a[fi][fj], 0, 0, 0);
            acc_b[fi][fj] = __builtin_amdgcn_mfma_f32_16x16x32_f16(azl[fi], beh[fj], acc_b[fi][fj], 0, 0, 0);
            acc_b[fi][fj] = __builtin_amdgcn_mfma_f32_16x16x32_f16(azh[fi], bel[fj], acc_b[fi][fj], 0, 0, 0);
        }
    __builtin_amdgcn_s_setprio(0);
}

__launch_bounds__(256, 2)
__global__ void vq_gemm_argmin(const _Float16* __restrict__ ZHb, const _Float16* __restrict__ ZLb,
                               const _Float16* __restrict__ EHb, const _Float16* __restrict__ ELb,
                               const float* __restrict__ zz,
                               unsigned long long* __restrict__ keys,
                               char* __restrict__ zfill) {
    __shared__ _Float16 lds[2][16384];                // 2 x 32KB
    __shared__ unsigned long long rowmin[128];

    // XCD-locality: xcd owns bm in [16x, 16x+16), sweeps bn
    int orig = blockIdx.x;
    int xcd = orig & 7;
    int loc = orig >> 3;                 // 0..1023
    int bm = xcd * 16 + (loc & 15);      // 0..127 (128-row Z slices)
    int bn = loc >> 4;                   // 0..63  (128-row E tiles)
    int m0 = bm * 128, n0v = bn * 128;

    int t = threadIdx.x;
    int lane = t & 63, wid = t >> 6;
    int wm = wid >> 1, wn = wid & 1;     // 2x2 waves of 64x64
    int g = lane >> 4, rr = lane & 15;

    // A slice = half of a 256-row blocked tile
    const char* zh = (const char*)ZHb + (size_t)(bm >> 1) * 131072 + (size_t)(bm & 1) * 2048;
    const char* zl = (const char*)ZLb + (size_t)(bm >> 1) * 131072 + (size_t)(bm & 1) * 2048;
    const char* eh = (const char*)EHb + (size_t)bn * 65536;
    const char* el = (const char*)ELb + (size_t)bn * 65536;
    char* zb = zfill + (size_t)orig * ZFILL_PER_BLK;   // this block's 60KB of enc zeros

    floatx4 acc_a[4][4], acc_b[4][4];
    #pragma unroll
    for (int i = 0; i < 4; ++i)
        #pragma unroll
        for (int jj = 0; jj < 4; ++jj) {
            acc_a[i][jj] = (floatx4){0.f, 0.f, 0.f, 0.f};
            acc_b[i][jj] = (floatx4){0.f, 0.f, 0.f, 0.f};
        }

    char* L0 = (char*)lds[0];
    char* L1 = (char*)lds[1];

    stage_chunk(zh, zl, eh, el, L0, t, 0);
    VM0; BAR;
    stage_chunk(zh, zl, eh, el, L1, t, 1); zfill2(zb, t, 0);  compute_chunk(L0, wm, wn, g, rr, acc_a, acc_b); VM0; BAR;
    stage_chunk(zh, zl, eh, el, L0, t, 2); zfill2(zb, t, 2);  compute_chunk(L1, wm, wn, g, rr, acc_a, acc_b); VM0; BAR;
    stage_chunk(zh, zl, eh, el, L1, t, 3); zfill2(zb, t, 4);  compute_chunk(L0, wm, wn, g, rr, acc_a, acc_b); VM0; BAR;
    stage_chunk(zh, zl, eh, el, L0, t, 4); zfill2(zb, t, 6);  compute_chunk(L1, wm, wn, g, rr, acc_a, acc_b); VM0; BAR;
    stage_chunk(zh, zl, eh, el, L1, t, 5); zfill2(zb, t, 8);  compute_chunk(L0, wm, wn, g, rr, acc_a, acc_b); VM0; BAR;
    stage_chunk(zh, zl, eh, el, L0, t, 6); zfill2(zb, t, 10); compute_chunk(L1, wm, wn, g, rr, acc_a, acc_b); VM0; BAR;
    stage_chunk(zh, zl, eh, el, L1, t, 7); zfill2(zb, t, 12); compute_chunk(L0, wm, wn, g, rr, acc_a, acc_b); VM0; BAR;
    {
        floatx4 z4 = {0.f, 0.f, 0.f, 0.f};
        __builtin_nontemporal_store(z4, (floatx4*)(zb + 14ull * 4096 + t * 16));
    }
    compute_chunk(L1, wm, wn, g, rr, acc_a, acc_b);

    if (t < 128) rowmin[t] = ~0ull;
    __syncthreads();

    constexpr float S_A = 1.0f / 65536.0f;       // 2^-16
    constexpr float S_B = 1.0f / 134217728.0f;   // 2^-27
    #pragma unroll
    for (int fi = 0; fi < 4; ++fi) {
        #pragma unroll
        for (int r = 0; r < 4; ++r) {
            int rowl = wm * 64 + fi * 16 + g * 4 + r;
            float zzv = zz[m0 + rowl];
            unsigned long long best = ~0ull;
            #pragma unroll
            for (int fj = 0; fj < 4; ++fj) {
                float dot = acc_a[fi][fj][r] * S_A + acc_b[fi][fj][r] * S_B;
                float d = zzv - 2.0f * dot;              // replicates ref fl(zz - fl(2*dot))
                unsigned int db = __float_as_uint(d);    // d > 0 -> bit order == float order
                unsigned int jg = (unsigned)(n0v + wn * 64 + fj * 16 + rr);
                unsigned long long key = ((unsigned long long)db << 32) | jg;
                if (key < best) best = key;
            }
            // cross-lane min over the 16 rr-lanes (same rowl) -> conflict-free atomic
            #pragma unroll
            for (int s = 1; s < 16; s <<= 1) {
                unsigned long long o = __shfl_xor(best, s, 64);
                if (o < best) best = o;
            }
            if (rr == 0) atomicMin(&rowmin[rowl], best);
        }
    }
    __syncthreads();
    if (t < 128) atomicMin(&keys[m0 + t], rowmin[t]);
}

// ---------------- z_q + loss partials + idx output + histogram (fused) ----------------
__global__ void vq_zq_loss(const float* __restrict__ z, const float* __restrict__ cb,
                           const unsigned long long* __restrict__ keys,
                           float* __restrict__ out0, float* __restrict__ parts,
                           float* __restrict__ out_idx, int* __restrict__ hist) {
    size_t i0 = ((size_t)blockIdx.x * 256 + threadIdx.x) * 8;
    int c   = (int)((i0 >> 13) & 255);
    int b   = (int)(i0 >> 21);
    int dhw = (int)(i0 & 8191);
    int nb  = b * DHW_ + dhw;
    int jj[8];
    #pragma unroll
    for (int e = 0; e < 8; ++e)
        jj[e] = (int)(unsigned)(keys[nb + e] & 0xFFFFFFFFull);
    float ls = 0.f;
    #pragma unroll
    for (int e = 0; e < 8; ++e) {
        float zq = cb[(size_t)jj[e] * K_ + c];
        float zt = z[i0 + e];
        float diff = zq - zt;        // fl, matches ref
        out0[i0 + e] = zt + diff;    // fl(z_t + fl(z_q - z_t))
        ls += diff * diff;
    }
    if (c == 0) {
        #pragma unroll
        for (int e = 0; e < 8; ++e) {
            out_idx[nb + e] = (float)jj[e];
            atomicAdd(&hist[jj[e]], 1);
        }
    }
    __shared__ float red[256];
    red[threadIdx.x] = ls;
    __syncthreads();
    for (int s = 128; s > 0; s >>= 1) {
        if (threadIdx.x < (unsigned)s) red[threadIdx.x] += red[threadIdx.x + s];
        __syncthreads();
    }
    if (threadIdx.x == 0) parts[blockIdx.x] = red[0];
}

// ---------------- loss + perplexity ----------------
__global__ void vq_finalize_scalars(const float* __restrict__ parts,
                                    const int* __restrict__ hist,
                                    float* __restrict__ out) {
    __shared__ double dred[256];
    int t = threadIdx.x;
    double ent = 0.0;
    for (int i = t; i < NE_; i += 256) {
        float em = (float)hist[i] * (1.0f / 16384.0f);   // exact (pow2)
        float term = em * logf(em + 1e-10f);
        ent += (double)term;
    }
    dred[t] = ent;
    __syncthreads();
    for (int s = 128; s > 0; s >>= 1) {
        if (t < s) dred[t] += dred[t + s];
        __syncthreads();
    }
    double entr = 0.0;
    if (t == 0) entr = dred[0];
    __syncthreads();
    double ls = 0.0;
    for (int i = t; i < NLOSS_BLOCKS; i += 256) ls += (double)parts[i];
    dred[t] = ls;
    __syncthreads();
    for (int s = 128; s > 0; s >>= 1) {
        if (t < s) dred[t] += dred[t + s];
        __syncthreads();
    }
    if (t == 0) {
        double m = dred[0] / 4194304.0;
        float m1 = (float)m;
        out[LOSS_OFF] = m1 + 0.25f * m1;
        out[PERP_OFF] = (float)exp(-entr);
    }
}

// ---------------- zero the scratch tail + head/tail slivers of enc ----------------
__global__ void vq_zero_tail(char* __restrict__ encb) {
    size_t i = (size_t)blockIdx.x * 256 + threadIdx.x;
    floatx4 z4 = {0.f, 0.f, 0.f, 0.f};
    char* base = encb + TAIL_START;
    for (size_t k = i; k < TAIL_F4; k += 131072)
        *(floatx4*)(base + k * 16) = z4;
    if (i == 0) {
        float2 z2 = {0.f, 0.f};
        *(float2*)encb = z2;                      // enc[0..1]
        *(float2*)(encb + 536870904ull) = z2;     // enc[last two]
    }
}

// ---------------- place the ones ----------------
__global__ void vq_write_ones(const float* __restrict__ idxf, float* __restrict__ enc) {
    int n = blockIdx.x * 256 + threadIdx.x;
    enc[(size_t)n * NE_ + (int)idxf[n]] = 1.0f;
}

extern "C" void kernel_launch(void* const* d_in, const int* in_sizes, int n_in,
                              void* d_out, int out_size, void* d_ws, size_t ws_size,
                              hipStream_t stream) {
    const float* z  = (const float*)d_in[0];
    const float* cb = (const float*)d_in[1];
    float* out = (float*)d_out;

    // 256B-aligned scratch base inside the enc-region tail
    char* scr = (char*)(((uintptr_t)(out + ENC_OFF) + 255) & ~(uintptr_t)255);
    _Float16* ZHb = (_Float16*)(scr + SCR_ZH);
    _Float16* ZLb = (_Float16*)(scr + SCR_ZL);
    _Float16* EHb = (_Float16*)(scr + SCR_EH);
    _Float16* ELb = (_Float16*)(scr + SCR_EL);
    float* zz = (float*)(scr + SCR_ZZ);
    unsigned long long* keys = (unsigned long long*)(scr + SCR_KEY);
    float* parts = (float*)(scr + SCR_PART);
    int* hist = (int*)(scr + SCR_HIST);
    float* out_idx = out + IDX_OFF;
    float* enc = out + ENC_OFF;
    char* encb = (char*)enc;

    vq_split<<<384, 256, 0, stream>>>(z, cb, ZHb, ZLb, EHb, ELb, zz, keys, hist);
    vq_gemm_argmin<<<8192, 256, 0, stream>>>(ZHb, ZLb, EHb, ELb, zz, keys, encb + 8);
    vq_zq_loss<<<NLOSS_BLOCKS, 256, 0, stream>>>(z, cb, keys, out, parts, out_idx, hist);
    vq_finalize_scalars<<<1, 256, 0, stream>>>(parts, hist, out);
    vq_zero_tail<<<512, 256, 0, stream>>>(encb);
    vq_write_ones<<<64, 256, 0, stream>>>(out_idx, enc);
}